// Round 3
// baseline (214.781 us; speedup 1.0000x reference)
//
#include <hip/hip_runtime.h>
#include <hip/hip_cooperative_groups.h>

namespace cg = cooperative_groups;

#define H 2048
#define W 2048
#define NBINS 256
#define NIMG 6
#define NTILE 384            // 6 imgs * 64 tiles
#define NBLK  768            // 2 blocks (col-halves) per tile
#define IMGPX (H * W)

typedef unsigned int u32;
typedef unsigned char u8;

// One fused cooperative kernel. Block b owns half-tile: tile = b>>1 (img,ty,tx),
// h = b&1 (col half). 256 rows x 128 cols. pbin lives in LDS the whole time.
__global__ __launch_bounds__(256, 3) void clahe_fused(const float* __restrict__ x,
                                                      u32* __restrict__ part,
                                                      float* __restrict__ luts,
                                                      float* __restrict__ out) {
    int bid  = blockIdx.x;
    int tile = bid >> 1;
    int h    = bid & 1;
    int tx   = tile & 7;
    int ty   = (tile >> 3) & 7;
    int img  = tile >> 6;

    int t  = threadIdx.x;
    int cg = t & 31;          // col group: 32 * float4 = 128 cols
    int rg = t >> 5;          // 8 rows in flight
    int wid = t >> 6;         // wave 0..3

    __shared__ u32 s_pbin[256][32];               // 32 KB packed u8 bins
    __shared__ alignas(16) u32 s_scratch[1024];   // 4 KB: wave hists / quad LUT
    __shared__ float s_wsum[4];
    __shared__ float s_tot;

    u32 (*whist)[NBINS] = (u32 (*)[NBINS])s_scratch;
    float4* lutq = (float4*)s_scratch;

    const float* base  = x   + (size_t)img * IMGPX;
    float*       obase = out + (size_t)img * IMGPX;
    int col0 = tx * 256 + h * 128;
    int row0 = ty * 256;

    // ---------------- Phase 1: histogram + pbin -> LDS ----------------
    for (int i = t; i < 1024; i += 256) s_scratch[i] = 0;
    __syncthreads();

    for (int it = 0; it < 32; ++it) {
        int lrow = rg + 8 * it;                    // 0..255
        int row  = row0 + lrow;
        float4 v = *(const float4*)(base + (size_t)row * W + col0 + cg * 4);
        // hist bins = clip(floor(x*256),0,255); x>=0 so trunc==floor
        int b0 = min((int)(v.x * 256.0f), 255);
        int b1 = min((int)(v.y * 256.0f), 255);
        int b2 = min((int)(v.z * 256.0f), 255);
        int b3 = min((int)(v.w * 256.0f), 255);
        atomicAdd(&whist[wid][b0], 1u);
        atomicAdd(&whist[wid][b1], 1u);
        atomicAdd(&whist[wid][b2], 1u);
        atomicAdd(&whist[wid][b3], 1u);
        // pbin = clip(floor(x*255),0,255), packed
        u32 p0 = min((int)(v.x * 255.0f), 255);
        u32 p1 = min((int)(v.y * 255.0f), 255);
        u32 p2 = min((int)(v.z * 255.0f), 255);
        u32 p3 = min((int)(v.w * 255.0f), 255);
        s_pbin[lrow][cg] = p0 | (p1 << 8) | (p2 << 16) | (p3 << 24);
    }
    __syncthreads();
    part[(size_t)bid * NBINS + t] =
        whist[0][t] + whist[1][t] + whist[2][t] + whist[3][t];

    cg::this_grid().sync();

    // ---------------- Phase 2: clip + cumsum -> LUT (blocks 0..383) ----------
    if (bid < NTILE) {
        const u32* p = part + (size_t)bid * 2 * NBINS;
        float hh = (float)(p[t] + p[NBINS + t]);
        float v = fminf(hh, 10240.0f);   // max_val = max(int(40*65536)//256,1)

        int lane = t & 63, w = t >> 6;
        #pragma unroll
        for (int off = 1; off < 64; off <<= 1) {
            float n = __shfl_up(v, off, 64);
            if (lane >= off) v += n;
        }
        if (lane == 63) s_wsum[w] = v;
        __syncthreads();
        float add = 0.0f;
        for (int ww = 0; ww < w; ++ww) add += s_wsum[ww];
        v += add;                          // inclusive cumsum of clipped
        if (t == 255) s_tot = v;
        __syncthreads();

        float e   = (65536.0f - s_tot) * (1.0f / 256.0f);
        float cum = v + (float)(t + 1) * e;
        float lut = floorf(fminf(fmaxf(cum * (255.0f / 65536.0f), 0.0f), 255.0f));
        luts[(size_t)bid * NBINS + t] = lut * (1.0f / 255.0f);   // fold /255
    }

    cg::this_grid().sync();

    // ---------------- Phase 3: bilinear apply from LDS pbin ----------------
    int x0 = (h == 0) ? max(tx - 1, 0) : tx;
    int x1 = (h == 0) ? tx : min(tx + 1, 7);
    float fx0 = (float)x0;
    int gcol = col0 + cg * 4;

    float wxa[4];
    #pragma unroll
    for (int k = 0; k < 4; ++k) {
        float xs = (gcol + k + 0.5f) * (1.0f / 256.0f) - 0.5f;
        xs = fminf(fmaxf(xs, 0.0f), 7.0f);
        wxa[k] = xs - fx0;
    }

    const float* lb = luts + (size_t)img * 64 * NBINS;

    for (int hy = 0; hy < 2; ++hy) {
        int y0 = (hy == 0) ? max(ty - 1, 0) : ty;
        int y1 = min(y0 + 1, 7);
        float fy0 = (float)y0;

        // stage quad-interleaved LUT: lutq[p] = (l[y0][x0], l[y0][x1], l[y1][x0], l[y1][x1])
        __syncthreads();
        {
            float a = lb[(y0 * 8 + x0) * NBINS + t];
            float b = lb[(y0 * 8 + x1) * NBINS + t];
            float c = lb[(y1 * 8 + x0) * NBINS + t];
            float d = lb[(y1 * 8 + x1) * NBINS + t];
            lutq[t] = make_float4(a, b, c, d);
        }
        __syncthreads();

        #pragma unroll 4
        for (int it = 0; it < 16; ++it) {
            int rloc = rg + 8 * it;                // 0..127 within half
            int lrow = hy * 128 + rloc;            // pbin LDS row
            int row  = row0 + lrow;                // global row
            float ys = (row + 0.5f) * (1.0f / 256.0f) - 0.5f;
            ys = fminf(fmaxf(ys, 0.0f), 7.0f);
            float wy = ys - fy0;

            u32 pw = s_pbin[lrow][cg];
            float r[4];
            #pragma unroll
            for (int k = 0; k < 4; ++k) {
                int p = (pw >> (8 * k)) & 255;
                float4 L = lutq[p];                // one ds_read_b128
                float wx = wxa[k];
                float ix0 = (1.0f - wx) * L.x + wx * L.y;
                float ix1 = (1.0f - wx) * L.z + wx * L.w;
                r[k] = (1.0f - wy) * ix0 + wy * ix1;  // /255 already folded
            }
            float4 o = {r[0], r[1], r[2], r[3]};
            *(float4*)(obase + (size_t)row * W + gcol) = o;
        }
    }
}

extern "C" void kernel_launch(void* const* d_in, const int* in_sizes, int n_in,
                              void* d_out, int out_size, void* d_ws, size_t ws_size,
                              hipStream_t stream) {
    const float* x = (const float*)d_in[0];
    float* out = (float*)d_out;

    u32*   part = (u32*)d_ws;                          // 768*256*4 = 768 KB
    float* luts = (float*)((char*)d_ws + (size_t)NBLK * NBINS * 4);  // 384 KB

    void* args[] = {(void*)&x, (void*)&part, (void*)&luts, (void*)&out};
    hipLaunchCooperativeKernel((void*)clahe_fused, dim3(NBLK), dim3(256),
                               args, 0, stream);
}

// Round 5
// 143.561 us; speedup vs baseline: 1.4961x; 1.4961x over previous
//
#include <hip/hip_runtime.h>

#define H 2048
#define W 2048
#define NBINS 256
#define NIMG 6
#define NTILE 384            // 6 imgs * 64 tiles
#define IMGPX (H * W)

typedef unsigned int u32;
typedef unsigned char u8;
typedef float f32x4 __attribute__((ext_vector_type(4)));

// ---------------- Kernel 1: per-tile partial histograms + pbin ----------------
// 1536 blocks = 4 per tile (64 rows each). Wave-private LDS hists -> plain
// store of the block's partial histogram (no memset, no global atomics).
// Also emits pbin = clip(floor(x*255),0,255) as packed u8 (image layout).
__global__ __launch_bounds__(256) void clahe_hist(const float* __restrict__ x,
                                                  u32* __restrict__ part,
                                                  u8* __restrict__ pbin) {
    int blk  = blockIdx.x;      // tile*4 + q
    int tile = blk >> 2;
    int q    = blk & 3;
    int tx   = tile & 7;
    int ty   = (tile >> 3) & 7;
    int img  = tile >> 6;
    const float* base = x + (size_t)img * IMGPX;
    u8* pb = pbin + (size_t)img * IMGPX;
    int row0 = ty * 256 + q * 64;
    int col0 = tx * 256;

    __shared__ u32 lh[4][NBINS];
    int t = threadIdx.x;
    for (int i = t; i < 4 * NBINS; i += 256) ((u32*)lh)[i] = 0;
    __syncthreads();

    int w  = t >> 6;    // wave id 0..3
    int cg = t & 63;    // 64 lanes cover 256 cols via float4
    for (int it = 0; it < 16; ++it) {
        int row = row0 + w + 4 * it;
        size_t off = (size_t)row * W + col0 + cg * 4;
        float4 v = *(const float4*)(base + off);
        // hist bins = clip(floor(x*256), 0, 255); x >= 0 so trunc == floor
        int b0 = min((int)(v.x * 256.0f), 255);
        int b1 = min((int)(v.y * 256.0f), 255);
        int b2 = min((int)(v.z * 256.0f), 255);
        int b3 = min((int)(v.w * 256.0f), 255);
        atomicAdd(&lh[w][b0], 1u);
        atomicAdd(&lh[w][b1], 1u);
        atomicAdd(&lh[w][b2], 1u);
        atomicAdd(&lh[w][b3], 1u);
        // pbin = clip(floor(x*255), 0, 255)
        u32 p0 = min((int)(v.x * 255.0f), 255);
        u32 p1 = min((int)(v.y * 255.0f), 255);
        u32 p2 = min((int)(v.z * 255.0f), 255);
        u32 p3 = min((int)(v.w * 255.0f), 255);
        *(u32*)(pb + off) = p0 | (p1 << 8) | (p2 << 16) | (p3 << 24);
    }
    __syncthreads();
    part[(size_t)blk * NBINS + t] =
        lh[0][t] + lh[1][t] + lh[2][t] + lh[3][t];
}

// ---------------- Kernel 2: sum partials, clip + cumsum -> LUT ----------------
// One block (256 threads) per tile; thread t owns bin t. LUT already /255.
__global__ __launch_bounds__(256) void clahe_lut(const u32* __restrict__ part,
                                                 float* __restrict__ luts) {
    int tile = blockIdx.x;
    int t = threadIdx.x;
    const u32* p = part + (size_t)tile * 4 * NBINS;
    float h = (float)(p[t] + p[NBINS + t] + p[2 * NBINS + t] + p[3 * NBINS + t]);
    float v = fminf(h, 10240.0f);   // max_val = max(int(40*65536)//256, 1)

    int lane = t & 63, wid = t >> 6;
    #pragma unroll
    for (int off = 1; off < 64; off <<= 1) {
        float n = __shfl_up(v, off, 64);
        if (lane >= off) v += n;
    }
    __shared__ float wsum[4];
    __shared__ float tot;
    if (lane == 63) wsum[wid] = v;
    __syncthreads();
    float add = 0.0f;
    for (int ww = 0; ww < wid; ++ww) add += wsum[ww];
    v += add;                        // inclusive cumsum of clipped
    if (t == 255) tot = v;
    __syncthreads();

    float e   = (65536.0f - tot) * (1.0f / 256.0f);   // excess/num_bins
    float cum = v + (float)(t + 1) * e;               // cumsum(clipped + e)
    float lut = floorf(fminf(fmaxf(cum * (255.0f / 65536.0f), 0.0f), 255.0f));
    luts[(size_t)tile * NBINS + t] = lut * (1.0f / 255.0f);  // fold /255
}

// ---------------- Kernel 3: bilinear LUT apply ----------------
// Block = 128 cols x 64 rows (aligned so the (y0,x0) cell is constant).
// 16 px/thread via uint4 pbin loads; nontemporal float4 stores (keep L3 for
// x/pbin — out is written once and never re-read).
__global__ __launch_bounds__(256) void clahe_apply(const u8* __restrict__ pbin,
                                                   const float* __restrict__ luts,
                                                   float* __restrict__ out) {
    int rx  = blockIdx.x * 128;
    int ry  = blockIdx.y * 64;
    int img = blockIdx.z;

    int yc = ry + 32, xc = rx + 64;
    int y0 = min(max((int)floorf((yc + 0.5f) * (1.0f / 256.0f) - 0.5f), 0), 7);
    int x0 = min(max((int)floorf((xc + 0.5f) * (1.0f / 256.0f) - 0.5f), 0), 7);
    int y1 = min(y0 + 1, 7), x1 = min(x0 + 1, 7);

    const float* lb = luts + (size_t)img * 64 * NBINS;
    __shared__ float l00[NBINS], l01[NBINS], l10[NBINS], l11[NBINS];
    int t = threadIdx.x;
    l00[t] = lb[(y0 * 8 + x0) * NBINS + t];
    l01[t] = lb[(y0 * 8 + x1) * NBINS + t];
    l10[t] = lb[(y1 * 8 + x0) * NBINS + t];
    l11[t] = lb[(y1 * 8 + x1) * NBINS + t];
    __syncthreads();

    const u8* pbase = pbin + (size_t)img * IMGPX;
    float*    obase = out  + (size_t)img * IMGPX;

    int cg = t & 7, rg = t >> 3;      // 8 threads * 16 px = 128 cols; 32 rows
    int col = rx + cg * 16;

    float fx0 = (float)x0;
    float wxa[16];
    #pragma unroll
    for (int k = 0; k < 16; ++k) {
        float xs = (col + k + 0.5f) * (1.0f / 256.0f) - 0.5f;
        xs = fminf(fmaxf(xs, 0.0f), 7.0f);
        wxa[k] = xs - fx0;
    }

    #pragma unroll
    for (int it = 0; it < 2; ++it) {
        int row = ry + rg + 32 * it;
        float ys = (row + 0.5f) * (1.0f / 256.0f) - 0.5f;
        ys = fminf(fmaxf(ys, 0.0f), 7.0f);
        float wy = ys - (float)y0;

        size_t off = (size_t)row * W + col;
        uint4 u = *(const uint4*)(pbase + off);
        u32 uw[4] = {u.x, u.y, u.z, u.w};

        float r[16];
        #pragma unroll
        for (int j = 0; j < 4; ++j) {
            #pragma unroll
            for (int k = 0; k < 4; ++k) {
                int idx = j * 4 + k;
                int p = (uw[j] >> (8 * k)) & 255;
                float wx = wxa[idx];
                float ix0 = (1.0f - wx) * l00[p] + wx * l01[p];
                float ix1 = (1.0f - wx) * l10[p] + wx * l11[p];
                r[idx] = (1.0f - wy) * ix0 + wy * ix1;   // /255 folded in LUT
            }
        }
        #pragma unroll
        for (int j = 0; j < 4; ++j) {
            f32x4 o = {r[4 * j], r[4 * j + 1], r[4 * j + 2], r[4 * j + 3]};
            __builtin_nontemporal_store(o, (f32x4*)(obase + off + 4 * j));
        }
    }
}

extern "C" void kernel_launch(void* const* d_in, const int* in_sizes, int n_in,
                              void* d_out, int out_size, void* d_ws, size_t ws_size,
                              hipStream_t stream) {
    const float* x = (const float*)d_in[0];
    float* out = (float*)d_out;

    const size_t PBIN_BYTES = (size_t)NIMG * IMGPX;           // 25.17 MB
    const size_t PART_BYTES = (size_t)NTILE * 4 * NBINS * 4;  // 1.57 MB

    u8*    pbin = (u8*)d_ws;
    u32*   part = (u32*)((char*)d_ws + PBIN_BYTES);
    float* luts = (float*)((char*)d_ws + PBIN_BYTES + PART_BYTES);

    clahe_hist<<<dim3(NTILE * 4), dim3(256), 0, stream>>>(x, part, pbin);
    clahe_lut<<<dim3(NTILE), dim3(256), 0, stream>>>(part, luts);
    clahe_apply<<<dim3(16, 32, NIMG), dim3(256), 0, stream>>>(pbin, luts, out);
}

// Round 6
// 53.102 us; speedup vs baseline: 4.0447x; 2.7035x over previous
//
#include <hip/hip_runtime.h>

#define H 2048
#define W 2048
#define NBINS 256
#define NIMG 6
#define NTILE 384            // 6 imgs * 64 tiles
#define IMGPX (H * W)

typedef unsigned int u32;
typedef unsigned char u8;
typedef float f32x4 __attribute__((ext_vector_type(4)));

// ---------------- Kernel 1: per-tile partial histograms + pbin ----------------
// 1536 blocks = 4 per tile (64 rows each). Wave-private LDS hists -> plain
// store of the block's partial histogram (no memset, no global atomics).
// Also emits pbin = clip(floor(x*255),0,255) as packed u8 (image layout).
__global__ __launch_bounds__(256) void clahe_hist(const float* __restrict__ x,
                                                  u32* __restrict__ part,
                                                  u8* __restrict__ pbin) {
    int blk  = blockIdx.x;      // tile*4 + q
    int tile = blk >> 2;
    int q    = blk & 3;
    int tx   = tile & 7;
    int ty   = (tile >> 3) & 7;
    int img  = tile >> 6;
    const float* base = x + (size_t)img * IMGPX;
    u8* pb = pbin + (size_t)img * IMGPX;
    int row0 = ty * 256 + q * 64;
    int col0 = tx * 256;

    __shared__ u32 lh[4][NBINS];
    int t = threadIdx.x;
    for (int i = t; i < 4 * NBINS; i += 256) ((u32*)lh)[i] = 0;
    __syncthreads();

    int w  = t >> 6;    // wave id 0..3
    int cg = t & 63;    // 64 lanes cover 256 cols via float4
    for (int it = 0; it < 16; ++it) {
        int row = row0 + w + 4 * it;
        size_t off = (size_t)row * W + col0 + cg * 4;
        float4 v = *(const float4*)(base + off);
        // hist bins = clip(floor(x*256), 0, 255); x >= 0 so trunc == floor
        int b0 = min((int)(v.x * 256.0f), 255);
        int b1 = min((int)(v.y * 256.0f), 255);
        int b2 = min((int)(v.z * 256.0f), 255);
        int b3 = min((int)(v.w * 256.0f), 255);
        atomicAdd(&lh[w][b0], 1u);
        atomicAdd(&lh[w][b1], 1u);
        atomicAdd(&lh[w][b2], 1u);
        atomicAdd(&lh[w][b3], 1u);
        // pbin = clip(floor(x*255), 0, 255)
        u32 p0 = min((int)(v.x * 255.0f), 255);
        u32 p1 = min((int)(v.y * 255.0f), 255);
        u32 p2 = min((int)(v.z * 255.0f), 255);
        u32 p3 = min((int)(v.w * 255.0f), 255);
        *(u32*)(pb + off) = p0 | (p1 << 8) | (p2 << 16) | (p3 << 24);
    }
    __syncthreads();
    part[(size_t)blk * NBINS + t] =
        lh[0][t] + lh[1][t] + lh[2][t] + lh[3][t];
}

// ---------------- Kernel 2: sum partials, clip + cumsum -> LUT ----------------
// One block (256 threads) per tile; thread t owns bin t. LUT already /255.
__global__ __launch_bounds__(256) void clahe_lut(const u32* __restrict__ part,
                                                 float* __restrict__ luts) {
    int tile = blockIdx.x;
    int t = threadIdx.x;
    const u32* p = part + (size_t)tile * 4 * NBINS;
    float h = (float)(p[t] + p[NBINS + t] + p[2 * NBINS + t] + p[3 * NBINS + t]);
    float v = fminf(h, 10240.0f);   // max_val = max(int(40*65536)//256, 1)

    int lane = t & 63, wid = t >> 6;
    #pragma unroll
    for (int off = 1; off < 64; off <<= 1) {
        float n = __shfl_up(v, off, 64);
        if (lane >= off) v += n;
    }
    __shared__ float wsum[4];
    __shared__ float tot;
    if (lane == 63) wsum[wid] = v;
    __syncthreads();
    float add = 0.0f;
    for (int ww = 0; ww < wid; ++ww) add += wsum[ww];
    v += add;                        // inclusive cumsum of clipped
    if (t == 255) tot = v;
    __syncthreads();

    float e   = (65536.0f - tot) * (1.0f / 256.0f);   // excess/num_bins
    float cum = v + (float)(t + 1) * e;               // cumsum(clipped + e)
    float lut = floorf(fminf(fmaxf(cum * (255.0f / 65536.0f), 0.0f), 255.0f));
    luts[(size_t)tile * NBINS + t] = lut * (1.0f / 255.0f);  // fold /255
}

// ---------------- Kernel 3: bilinear LUT apply ----------------
// Block = 128 cols x 64 rows (aligned so the (y0,x0) cell is constant).
// 4 px/thread, CONSECUTIVE lanes -> consecutive 16B chunks, so every store
// instruction covers whole cache lines (nt-store safe). pbin-only input.
__global__ __launch_bounds__(256) void clahe_apply(const u8* __restrict__ pbin,
                                                   const float* __restrict__ luts,
                                                   float* __restrict__ out) {
    int rx  = blockIdx.x * 128;
    int ry  = blockIdx.y * 64;
    int img = blockIdx.z;

    int yc = ry + 32, xc = rx + 64;
    int y0 = min(max((int)floorf((yc + 0.5f) * (1.0f / 256.0f) - 0.5f), 0), 7);
    int x0 = min(max((int)floorf((xc + 0.5f) * (1.0f / 256.0f) - 0.5f), 0), 7);
    int y1 = min(y0 + 1, 7), x1 = min(x0 + 1, 7);

    const float* lb = luts + (size_t)img * 64 * NBINS;
    __shared__ float l00[NBINS], l01[NBINS], l10[NBINS], l11[NBINS];
    int t = threadIdx.x;
    l00[t] = lb[(y0 * 8 + x0) * NBINS + t];
    l01[t] = lb[(y0 * 8 + x1) * NBINS + t];
    l10[t] = lb[(y1 * 8 + x0) * NBINS + t];
    l11[t] = lb[(y1 * 8 + x1) * NBINS + t];
    __syncthreads();

    const u8* pbase = pbin + (size_t)img * IMGPX;
    float*    obase = out  + (size_t)img * IMGPX;

    int cg = t & 31, rg = t >> 5;     // 32 lanes * 4 px = 128 cols; 8 rows/iter
    int col = rx + cg * 4;

    float fx0 = (float)x0;
    float wxa[4];
    #pragma unroll
    for (int k = 0; k < 4; ++k) {
        float xs = (col + k + 0.5f) * (1.0f / 256.0f) - 0.5f;
        xs = fminf(fmaxf(xs, 0.0f), 7.0f);
        wxa[k] = xs - fx0;
    }

    #pragma unroll
    for (int it = 0; it < 8; ++it) {
        int row = ry + rg + 8 * it;
        float ys = (row + 0.5f) * (1.0f / 256.0f) - 0.5f;
        ys = fminf(fmaxf(ys, 0.0f), 7.0f);
        float wy = ys - (float)y0;

        size_t off = (size_t)row * W + col;
        u32 pw = *(const u32*)(pbase + off);

        float r[4];
        #pragma unroll
        for (int k = 0; k < 4; ++k) {
            int p = (pw >> (8 * k)) & 255;
            float wx = wxa[k];
            float ix0 = (1.0f - wx) * l00[p] + wx * l01[p];
            float ix1 = (1.0f - wx) * l10[p] + wx * l11[p];
            r[k] = (1.0f - wy) * ix0 + wy * ix1;   // /255 folded in LUT
        }
        f32x4 o = {r[0], r[1], r[2], r[3]};
        __builtin_nontemporal_store(o, (f32x4*)(obase + off));
    }
}

extern "C" void kernel_launch(void* const* d_in, const int* in_sizes, int n_in,
                              void* d_out, int out_size, void* d_ws, size_t ws_size,
                              hipStream_t stream) {
    const float* x = (const float*)d_in[0];
    float* out = (float*)d_out;

    const size_t PBIN_BYTES = (size_t)NIMG * IMGPX;           // 25.17 MB
    const size_t PART_BYTES = (size_t)NTILE * 4 * NBINS * 4;  // 1.57 MB

    u8*    pbin = (u8*)d_ws;
    u32*   part = (u32*)((char*)d_ws + PBIN_BYTES);
    float* luts = (float*)((char*)d_ws + PBIN_BYTES + PART_BYTES);

    clahe_hist<<<dim3(NTILE * 4), dim3(256), 0, stream>>>(x, part, pbin);
    clahe_lut<<<dim3(NTILE), dim3(256), 0, stream>>>(part, luts);
    clahe_apply<<<dim3(16, 32, NIMG), dim3(256), 0, stream>>>(pbin, luts, out);
}